// Round 6
// baseline (561.033 us; speedup 1.0000x reference)
//
#include <hip/hip_runtime.h>

#define BB 16
#define CC 16
#define HH 384
#define WW 384
#define HWSZ (HH*WW)
#define CHW (CC*HWSZ)
#define NPIX (BB*CHW)
#define KS 11

#define K2_THREADS 256
#define K2_HSEGS 12
#define K2_SEGH (HH/K2_HSEGS)    // 32 rows per segment (halo 10/32 = 31%)
#define W8 (WW/8)
#define ROWU4 (WW/8)

#define LDSW 408                 // 8 left pad + 384 + 16 right pad (cols)

typedef unsigned short ushortT;

// ---- bf16 helpers (raw-bit, RNE) -----------------------------------------
__device__ __forceinline__ ushortT f2bf(float f) {
    union { float f; unsigned u; } c; c.f = f;
    unsigned r = c.u + 0x7FFFu + ((c.u >> 16) & 1u);
    return (ushortT)(r >> 16);
}
__device__ __forceinline__ void unpk2(unsigned u, float& lo, float& hi) {
    union { unsigned u; float f; } a, b;
    a.u = u << 16; b.u = u & 0xFFFF0000u;
    lo = a.f; hi = b.f;
}
__device__ __forceinline__ unsigned pk2(float lo, float hi) {
    return ((unsigned)f2bf(hi) << 16) | (unsigned)f2bf(lo);
}
__device__ __forceinline__ void unpk8(const uint4& q, float* v) {
    unpk2(q.x, v[0], v[1]); unpk2(q.y, v[2], v[3]);
    unpk2(q.z, v[4], v[5]); unpk2(q.w, v[6], v[7]);
}
__device__ __forceinline__ uint4 pk8(const float* v) {
    uint4 q;
    q.x = pk2(v[0], v[1]); q.y = pk2(v[2], v[3]);
    q.z = pk2(v[4], v[5]); q.w = pk2(v[6], v[7]);
    return q;
}

// ---------------------------------------------------------------------------
// K1: softmax over C + 11-tap ConvW (center 0).  Wave = one (b,h) row;
// lane g in [0,48) owns 8 cols (uint4 bf16) for all 16 channels.
// In-register softmax; conv halo via one LDS round-trip (write bf16x8,
// barrier, read 3 aligned uint4 per channel).  No shuffles.
// F32IN: iter-0 variant reads f32 x0 directly and also emits x0b (bf16).
// ---------------------------------------------------------------------------
template<bool F32IN>
__global__ __launch_bounds__(256) void k_smax_convw(
    const void* __restrict__ xin, ushortT* __restrict__ t,
    ushortT* __restrict__ x0b,
    const float* __restrict__ spacings, const float* __restrict__ invtheta)
{
    __shared__ ushortT p_lds[4][CC][LDSW];   // 52 KB; padded col index = col+8

    const int lane = threadIdx.x & 63;
    const int r    = threadIdx.x >> 6;       // 4 rows per block
    const int h    = blockIdx.x * 4 + r;
    const int b    = blockIdx.y;
    const bool act = lane < 48;
    const int g    = act ? lane : 47;        // clamped for safe addresses

    const float sc = spacings[b * 2 + 1] * invtheta[1];  // W axis = spatial axis 1
    float kw[KS];
#pragma unroll
    for (int j = 0; j < KS; ++j) { float d = sc * (float)(j - 5); kw[j] = __expf(-0.5f * d * d); }
    kw[5] = 0.f;

    const size_t base = (size_t)b * CHW + (size_t)h * WW + (size_t)g * 8;

    // ---- load x (all channels), packed bf16 ----
    uint4 xq[CC];
    if (F32IN) {
        const float* xf = (const float*)xin;
#pragma unroll
        for (int c = 0; c < CC; ++c) {
            const float4 A = *(const float4*)(xf + base + (size_t)c * HWSZ);
            const float4 B = *(const float4*)(xf + base + (size_t)c * HWSZ + 4);
            uint4 q;
            q.x = pk2(A.x, A.y); q.y = pk2(A.z, A.w);
            q.z = pk2(B.x, B.y); q.w = pk2(B.z, B.w);
            xq[c] = q;
            if (act) *(uint4*)(x0b + base + (size_t)c * HWSZ) = q;
        }
    } else {
        const ushortT* xb = (const ushortT*)xin;
#pragma unroll
        for (int c = 0; c < CC; ++c)
            xq[c] = *(const uint4*)(xb + base + (size_t)c * HWSZ);
    }

    // ---- in-register softmax over channels ----
    float m[8];
    unpk8(xq[0], m);
#pragma unroll
    for (int c = 1; c < CC; ++c) {
        float v[8]; unpk8(xq[c], v);
#pragma unroll
        for (int k = 0; k < 8; ++k) m[k] = fmaxf(m[k], v[k]);
    }
    float s[8];
#pragma unroll
    for (int k = 0; k < 8; ++k) s[k] = 0.f;
#pragma unroll
    for (int c = 0; c < CC; ++c) {
        float v[8]; unpk8(xq[c], v);
#pragma unroll
        for (int k = 0; k < 8; ++k) { v[k] = __expf(v[k] - m[k]); s[k] += v[k]; }
        xq[c] = pk8(v);
    }
    float inv[8];
#pragma unroll
    for (int k = 0; k < 8; ++k) inv[k] = 1.0f / s[k];

    // ---- stage p into LDS (pads zeroed by idle lanes) ----
    if (act) {
#pragma unroll
        for (int c = 0; c < CC; ++c) {
            float v[8]; unpk8(xq[c], v);
#pragma unroll
            for (int k = 0; k < 8; ++k) v[k] *= inv[k];
            *(uint4*)&p_lds[r][c][8 + g * 8] = pk8(v);
        }
    } else {
        const int q = lane - 48;             // 16 idle lanes -> 16 channels
        const uint4 z = make_uint4(0u, 0u, 0u, 0u);
        *(uint4*)&p_lds[r][q][0]   = z;      // cols -8..-1
        *(uint4*)&p_lds[r][q][392] = z;      // cols 384..391
        *(uint4*)&p_lds[r][q][400] = z;      // cols 392..399
    }
    __syncthreads();

    // ---- ConvW from LDS window [8g-8, 8g+16), store t' ----
    if (act) {
        ushortT* tb = t + base;
#pragma unroll
        for (int c = 0; c < CC; ++c) {
            const ushortT* row = &p_lds[r][c][g * 8];   // padded idx 8g = col 8g-8
            const uint4 q0 = *(const uint4*)(row);
            const uint4 q1 = *(const uint4*)(row + 8);
            const uint4 q2 = *(const uint4*)(row + 16);
            float w[24];
            unpk8(q0, w); unpk8(q1, w + 8); unpk8(q2, w + 16);
            float o[8];
#pragma unroll
            for (int k = 0; k < 8; ++k) {
                float acc = 0.f;
#pragma unroll
                for (int j = 0; j < KS; ++j) {
                    if (j == 5) continue;
                    acc = fmaf(kw[j], w[k + 3 + j], acc);
                }
                o[k] = acc;
            }
            *(uint4*)(tb + (size_t)c * HWSZ) = pk8(o);
        }
    }
}

// ---------------------------------------------------------------------------
// K2: ConvH (rolling bf16x8 window) + x = x0b + sw*conv.  bf16 in/out.
// ---------------------------------------------------------------------------
__global__ __launch_bounds__(K2_THREADS) void k_convh_add(
    const ushortT* __restrict__ t, const ushortT* __restrict__ x0b,
    ushortT* __restrict__ xout,
    const float* __restrict__ spacings, const float* __restrict__ invtheta,
    const float* __restrict__ swp)
{
    const int colIdx = blockIdx.x * K2_THREADS + threadIdx.x;
    const int c  = colIdx / W8;
    const int w8 = colIdx - c * W8;
    const int b  = blockIdx.z;
    const int h0 = blockIdx.y * K2_SEGH;

    const float sw = swp[0];
    const float sc = spacings[b * 2 + 0] * invtheta[0];  // H axis = spatial axis 0
    float kh[KS];
#pragma unroll
    for (int j = 0; j < KS; ++j) { float d = sc * (float)(j - 5); kh[j] = __expf(-0.5f * d * d); }
    kh[5] = 0.f;

    const size_t base = (size_t)(b * CC + c) * HWSZ + (size_t)w8 * 8;
    const uint4* tb = (const uint4*)(t    + base);
    const uint4* ub = (const uint4*)(x0b  + base);
    uint4*       ob = (uint4*)      (xout + base);

    const uint4 z4 = make_uint4(0u, 0u, 0u, 0u);
    uint4 win[KS];
#pragma unroll
    for (int j = 0; j < KS; ++j) {
        const int rr = h0 + j - 5;
        win[j] = ((unsigned)rr < HH) ? tb[(size_t)rr * ROWU4] : z4;
    }

#pragma unroll 4
    for (int h = h0; h < h0 + K2_SEGH; ++h) {
        const int nr = h + 6;
        const uint4 nt = (nr < HH) ? tb[(size_t)nr * ROWU4] : z4;   // prefetch
        const uint4 u  = ub[(size_t)h * ROWU4];

        float acc[8];
#pragma unroll
        for (int k = 0; k < 8; ++k) acc[k] = 0.f;
#pragma unroll
        for (int j = 0; j < KS; ++j) {
            if (j == 5) continue;
            float e[8]; unpk8(win[j], e);
            const float kj = kh[j];
#pragma unroll
            for (int k = 0; k < 8; ++k) acc[k] = fmaf(kj, e[k], acc[k]);
        }
        float uu[8]; unpk8(u, uu);
        float o[8];
#pragma unroll
        for (int k = 0; k < 8; ++k) o[k] = fmaf(sw, acc[k], uu[k]);
        ob[(size_t)h * ROWU4] = pk8(o);

#pragma unroll
        for (int j = 0; j < KS - 1; ++j) win[j] = win[j + 1];
        win[KS - 1] = nt;
    }
}

// ---------------------------------------------------------------------------
// K3: log_softmax over C, bf16 in -> f32 out.  8 pixels per thread.
// ---------------------------------------------------------------------------
__global__ __launch_bounds__(256) void k_final(
    const ushortT* __restrict__ xf, float* __restrict__ out)
{
    const int p8 = blockIdx.x * 256 + threadIdx.x;
    if (p8 >= (BB * HWSZ) / 8) return;
    const int b  = p8 / (HWSZ / 8);
    const int r8 = p8 - b * (HWSZ / 8);
    const size_t base = (size_t)b * CHW + (size_t)r8 * 8;

    float v[CC][8];
#pragma unroll
    for (int c = 0; c < CC; ++c) {
        const uint4 q = *(const uint4*)(xf + base + (size_t)c * HWSZ);
        unpk8(q, v[c]);
    }
#pragma unroll
    for (int k = 0; k < 8; ++k) {
        float m = v[0][k];
#pragma unroll
        for (int c = 1; c < CC; ++c) m = fmaxf(m, v[c][k]);
        float s = 0.f;
#pragma unroll
        for (int c = 0; c < CC; ++c) s += __expf(v[c][k] - m);
        const float l = m + __logf(s);
#pragma unroll
        for (int c = 0; c < CC; ++c) v[c][k] -= l;
    }
#pragma unroll
    for (int c = 0; c < CC; ++c) {
        float* op = out + base + (size_t)c * HWSZ;
        *(float4*)op       = make_float4(v[c][0], v[c][1], v[c][2], v[c][3]);
        *(float4*)(op + 4) = make_float4(v[c][4], v[c][5], v[c][6], v[c][7]);
    }
}

// ---------------------------------------------------------------------------
extern "C" void kernel_launch(void* const* d_in, const int* in_sizes, int n_in,
                              void* d_out, int out_size, void* d_ws, size_t ws_size,
                              hipStream_t stream)
{
    const float* x0   = (const float*)d_in[0];  // (B,C,H,W) unaries f32
    const float* spac = (const float*)d_in[1];  // (B,2)
    const float* sw   = (const float*)d_in[2];  // scalar
    const float* it   = (const float*)d_in[3];  // (2,)

    ushortT* x0b = (ushortT*)d_ws;        // bf16 copy of x0 (75.5 MB)
    ushortT* t   = x0b + (size_t)NPIX;    // bf16 smoothed probs (75.5 MB)
    ushortT* xb  = (ushortT*)d_out;       // bf16 evolving x (first half of d_out)
    float*   out = (float*)d_out;         // final f32 output

    dim3 g1(HH / 4, BB);                  // (96,16), 256 threads = 4 row-waves
    dim3 g2(CC * W8 / K2_THREADS, K2_HSEGS, BB);   // (3, 12, 16)

    // iter 0: reads f32 x0 directly; also emits x0b (bf16)
    k_smax_convw<true><<<g1, dim3(256), 0, stream>>>(x0, t, x0b, spac, it);
    k_convh_add<<<g2, dim3(K2_THREADS), 0, stream>>>(t, x0b, xb, spac, it, sw);

    for (int n = 1; n < 5; ++n) {
        k_smax_convw<false><<<g1, dim3(256), 0, stream>>>(xb, t, x0b, spac, it);
        // last iteration writes x5 over x0b (element-wise same-thread RAW — safe);
        // x0b is regenerated every launch by iter-0, so replay-deterministic.
        k_convh_add<<<g2, dim3(K2_THREADS), 0, stream>>>(
            t, x0b, (n == 4) ? x0b : xb, spac, it, sw);
    }
    const int np8 = (BB * HWSZ) / 8;
    k_final<<<(np8 + 255) / 256, 256, 0, stream>>>(x0b, out);
}

// Round 7
// 533.130 us; speedup vs baseline: 1.0523x; 1.0523x over previous
//
#include <hip/hip_runtime.h>

#define BB 16
#define CC 16
#define HH 384
#define WW 384
#define HWSZ (HH*WW)
#define CHW (CC*HWSZ)
#define NPIX (BB*CHW)
#define KS 11

#define FT 768             // threads per fused block (16 c x 48 col-groups)
#define ROWS 16            // output rows per block
#define HSEGS (HH/ROWS)    // 24 -> grid 384 blocks
#define SROW 400           // LDS row stride (f32 words): [8 zero pad][384][8 zero pad]

typedef unsigned short ushortT;

// ---- bf16 helpers (raw-bit, RNE) -----------------------------------------
__device__ __forceinline__ ushortT f2bf(float f) {
    union { float f; unsigned u; } c; c.f = f;
    unsigned r = c.u + 0x7FFFu + ((c.u >> 16) & 1u);
    return (ushortT)(r >> 16);
}
__device__ __forceinline__ void unpk2(unsigned u, float& lo, float& hi) {
    union { unsigned u; float f; } a, b;
    a.u = u << 16; b.u = u & 0xFFFF0000u;
    lo = a.f; hi = b.f;
}
__device__ __forceinline__ unsigned pk2(float lo, float hi) {
    return ((unsigned)f2bf(hi) << 16) | (unsigned)f2bf(lo);
}
__device__ __forceinline__ void unpk8(const uint4& q, float* v) {
    unpk2(q.x, v[0], v[1]); unpk2(q.y, v[2], v[3]);
    unpk2(q.z, v[4], v[5]); unpk2(q.w, v[6], v[7]);
}
__device__ __forceinline__ uint4 pk8(const float* v) {
    uint4 q;
    q.x = pk2(v[0], v[1]); q.y = pk2(v[2], v[3]);
    q.z = pk2(v[4], v[5]); q.w = pk2(v[6], v[7]);
    return q;
}

// ---------------------------------------------------------------------------
// Fused CRF step.  MODE 0: in0 = x0 (f32); emits x0b (bf16) and t0.
//                  MODE 1: in0 = t_n (bf16), x0b; emits t_{n+1}.
//                  MODE 2: in0 = t_4 (bf16), x0b; emits log_softmax(x5) f32.
// Block = (b, 16-row band).  Per row: A) ConvH via rolling uint4 register
// window + x0 add -> f32 LDS row; barrier; B) per-column softmax in-place
// (stride-1-per-lane scalar LDS, conflict-free); barrier; C) ConvW from LDS
// -> bf16 t'.  x is never materialized in global memory.
// ---------------------------------------------------------------------------
template<int MODE>
__global__ __launch_bounds__(FT) void k_fused(
    const void* __restrict__ in0, const ushortT* __restrict__ x0b,
    void* __restrict__ outp, ushortT* __restrict__ x0b_out,
    const float* __restrict__ spacings, const float* __restrict__ invtheta,
    const float* __restrict__ swp)
{
    __shared__ float xp[2][CC][SROW];   // 50 KB, double buffered

    const int t  = threadIdx.x;
    const int b  = blockIdx.y;
    const int h0 = blockIdx.x * ROWS;

    // zero the 8-word pads on both sides of every row, both buffers (once)
    if (t < 2 * CC * 16) {
        const int buf = t >> 8, rem = t & 255, c = rem >> 4, k = rem & 15;
        const int idx = (k < 8) ? k : (384 + k);       // 0..7 | 392..399
        xp[buf][c][idx] = 0.f;
    }

    const float sw  = swp[0];
    const float sch = spacings[b * 2 + 0] * invtheta[0];   // H axis
    const float scw = spacings[b * 2 + 1] * invtheta[1];   // W axis
    float kh[KS], kw[KS];
#pragma unroll
    for (int j = 0; j < KS; ++j) {
        float dh = sch * (float)(j - 5); kh[j] = __expf(-0.5f * dh * dh);
        float dw = scw * (float)(j - 5); kw[j] = __expf(-0.5f * dw * dw);
    }
    kh[5] = 0.f; kw[5] = 0.f;

    // phase identities
    const int ca = t / 48, ga = t - ca * 48;   // A: (channel, 8-col group)
    const int hc = t / WW, wc = t - hc * WW;   // C: (channel half, column)

    const size_t cbase = (size_t)b * CHW + (size_t)ca * HWSZ + (size_t)ga * 8;

    // rolling window over t rows (MODE >= 1)
    const uint4 z4 = make_uint4(0u, 0u, 0u, 0u);
    uint4 win[KS];
    if (MODE >= 1) {
        const ushortT* tin = (const ushortT*)in0;
#pragma unroll
        for (int j = 0; j < KS; ++j) {
            const int r = h0 + j - 5;
            win[j] = ((unsigned)r < HH) ? *(const uint4*)(tin + cbase + (size_t)r * WW) : z4;
        }
    }

    __syncthreads();   // pads visible

    int buf = 0;
    for (int h = h0; h < h0 + ROWS; ++h) {
        // ---------------- A: x-row -> LDS (f32) ----------------
        if (MODE == 0) {
            const float* xf = (const float*)in0;
            const float4 A = *(const float4*)(xf + cbase + (size_t)h * WW);
            const float4 B = *(const float4*)(xf + cbase + (size_t)h * WW + 4);
            float v[8] = {A.x, A.y, A.z, A.w, B.x, B.y, B.z, B.w};
            *(uint4*)(x0b_out + cbase + (size_t)h * WW) = pk8(v);
            *(float4*)&xp[buf][ca][8 + ga * 8]     = A;
            *(float4*)&xp[buf][ca][8 + ga * 8 + 4] = B;
        } else {
            const ushortT* tin = (const ushortT*)in0;
            const int nr = h + 6;
            const uint4 nt = (nr < HH) ? *(const uint4*)(tin + cbase + (size_t)nr * WW) : z4;
            const uint4 uq = *(const uint4*)(x0b + cbase + (size_t)h * WW);
            float acc[8];
#pragma unroll
            for (int k = 0; k < 8; ++k) acc[k] = 0.f;
#pragma unroll
            for (int j = 0; j < KS; ++j) {
                if (j == 5) continue;
                float e[8]; unpk8(win[j], e);
                const float kj = kh[j];
#pragma unroll
                for (int k = 0; k < 8; ++k) acc[k] = fmaf(kj, e[k], acc[k]);
            }
            float uu[8]; unpk8(uq, uu);
            float xv[8];
#pragma unroll
            for (int k = 0; k < 8; ++k) xv[k] = fmaf(sw, acc[k], uu[k]);
            *(float4*)&xp[buf][ca][8 + ga * 8]     = make_float4(xv[0], xv[1], xv[2], xv[3]);
            *(float4*)&xp[buf][ca][8 + ga * 8 + 4] = make_float4(xv[4], xv[5], xv[6], xv[7]);
#pragma unroll
            for (int j = 0; j < KS - 1; ++j) win[j] = win[j + 1];
            win[KS - 1] = nt;
        }
        __syncthreads();

        // ---------------- B: per-column softmax (in-place) ----------------
        if (t < WW) {
            float xr[CC];
#pragma unroll
            for (int c = 0; c < CC; ++c) xr[c] = xp[buf][c][8 + t];
            float m = xr[0];
#pragma unroll
            for (int c = 1; c < CC; ++c) m = fmaxf(m, xr[c]);
            if (MODE == 2) {
                float s = 0.f;
#pragma unroll
                for (int c = 0; c < CC; ++c) s += __expf(xr[c] - m);
                const float l = m + __logf(s);
                float* op = (float*)outp + (size_t)b * CHW + (size_t)h * WW + t;
#pragma unroll
                for (int c = 0; c < CC; ++c) op[(size_t)c * HWSZ] = xr[c] - l;
            } else {
                float v[CC]; float s = 0.f;
#pragma unroll
                for (int c = 0; c < CC; ++c) { v[c] = __expf(xr[c] - m); s += v[c]; }
                const float inv = 1.0f / s;
#pragma unroll
                for (int c = 0; c < CC; ++c) xp[buf][c][8 + t] = v[c] * inv;
            }
        }
        __syncthreads();

        // ---------------- C: ConvW -> t' (bf16) ----------------
        if (MODE <= 1) {
            ushortT* to = (ushortT*)outp + (size_t)b * CHW + (size_t)h * WW + wc;
#pragma unroll
            for (int cc = 0; cc < 8; ++cc) {
                const int c = hc * 8 + cc;
                float acc = 0.f;
#pragma unroll
                for (int j = 0; j < KS; ++j) {
                    if (j == 5) continue;
                    acc = fmaf(kw[j], xp[buf][c][8 + wc + j - 5], acc);
                }
                to[(size_t)c * HWSZ] = f2bf(acc);
            }
        }
        buf ^= 1;
    }
}

// ---------------------------------------------------------------------------
extern "C" void kernel_launch(void* const* d_in, const int* in_sizes, int n_in,
                              void* d_out, int out_size, void* d_ws, size_t ws_size,
                              hipStream_t stream)
{
    const float* x0   = (const float*)d_in[0];  // (B,C,H,W) f32
    const float* spac = (const float*)d_in[1];  // (B,2)
    const float* sw   = (const float*)d_in[2];  // scalar
    const float* it   = (const float*)d_in[3];  // (2,)

    ushortT* tA  = (ushortT*)d_ws;              // 75.5 MB
    ushortT* tB  = tA + (size_t)NPIX;           // 75.5 MB
    ushortT* x0b = tB + (size_t)NPIX;           // 75.5 MB
    float*   out = (float*)d_out;

    dim3 gf(HSEGS, BB);   // (24,16) = 384 blocks
    dim3 bf(FT);

    // iter 1: t0 = ConvW(softmax(x0)); also emits x0b
    k_fused<0><<<gf, bf, 0, stream>>>(x0, nullptr, tA, x0b, spac, it, sw);
    // iters 2..5 inner: t_{n+1} = ConvW(softmax(x0b + sw*ConvH(t_n)))
    k_fused<1><<<gf, bf, 0, stream>>>(tA, x0b, tB, nullptr, spac, it, sw);
    k_fused<1><<<gf, bf, 0, stream>>>(tB, x0b, tA, nullptr, spac, it, sw);
    k_fused<1><<<gf, bf, 0, stream>>>(tA, x0b, tB, nullptr, spac, it, sw);
    k_fused<1><<<gf, bf, 0, stream>>>(tB, x0b, tA, nullptr, spac, it, sw);
    // final: out = log_softmax(x0b + sw*ConvH(t4))
    k_fused<2><<<gf, bf, 0, stream>>>(tA, x0b, out, nullptr, spac, it, sw);
}

// Round 8
// 428.933 us; speedup vs baseline: 1.3080x; 1.2429x over previous
//
#include <hip/hip_runtime.h>

#define BB 16
#define CC 16
#define HH 384
#define WW 384
#define HWSZ (HH*WW)
#define CHW (CC*HWSZ)
#define NPIX (BB*CHW)

#define FT 768             // 16 channels x 48 col-groups
#define ROWS 12            // rows per block -> 32x16 = 512 blocks
#define HSEGS (HH/ROWS)
#define SROW 408           // LDS row: 8 pad | 384 | 16 pad (bf16 elems)

typedef unsigned short ushortT;

// ---- bf16 helpers (raw-bit, RNE) -----------------------------------------
__device__ __forceinline__ float bf2f(ushortT h) {
    union { unsigned u; float f; } c; c.u = ((unsigned)h) << 16; return c.f;
}
__device__ __forceinline__ ushortT f2bf(float f) {
    union { float f; unsigned u; } c; c.f = f;
    unsigned r = c.u + 0x7FFFu + ((c.u >> 16) & 1u);
    return (ushortT)(r >> 16);
}
__device__ __forceinline__ void unpk2(unsigned u, float& lo, float& hi) {
    union { unsigned u; float f; } a, b;
    a.u = u << 16; b.u = u & 0xFFFF0000u;
    lo = a.f; hi = b.f;
}
__device__ __forceinline__ unsigned pk2(float lo, float hi) {
    return ((unsigned)f2bf(hi) << 16) | (unsigned)f2bf(lo);
}
__device__ __forceinline__ void unpk8(const uint4& q, float* v) {
    unpk2(q.x, v[0], v[1]); unpk2(q.y, v[2], v[3]);
    unpk2(q.z, v[4], v[5]); unpk2(q.w, v[6], v[7]);
}
__device__ __forceinline__ uint4 pk8(const float* v) {
    uint4 q;
    q.x = pk2(v[0], v[1]); q.y = pk2(v[2], v[3]);
    q.z = pk2(v[4], v[5]); q.w = pk2(v[6], v[7]);
    return q;
}

// ---------------------------------------------------------------------------
// Fused CRF step.  MODE 0: in0 = x0 (f32); emits x0b (bf16) and t0.
//                  MODE 1: in0 = t_n (bf16) + x0b; emits t_{n+1}.
//                  MODE 2: in0 = t_4 (bf16) + x0b; emits log_softmax(x5) f32.
// Per row: A) ConvH rolling uint4 window + add -> bf16 LDS row (1 ds_write_b128)
//          B) per-column softmax, thread-pairs split channels, shfl_xor combine
//          C) ConvW from 3 aligned ds_read_b128 -> one uint4 global store
// LDS bf16 double-buffered (26 KB); C(h) overlaps A(h+1).
// ---------------------------------------------------------------------------
template<int MODE>
__global__ __launch_bounds__(FT) void k_fused(
    const void* __restrict__ in0, const ushortT* __restrict__ x0b,
    void* __restrict__ outp, ushortT* __restrict__ x0b_out,
    const float* __restrict__ spacings, const float* __restrict__ invtheta,
    const float* __restrict__ swp)
{
    __shared__ ushortT xp[2][CC][SROW];        // 26112 B
    __shared__ __align__(16) float l_lds[WW];  // MODE 2 only

    const int t  = threadIdx.x;
    const int b  = blockIdx.y;
    const int h0 = blockIdx.x * ROWS;

    // zero the pads: 2 buf x 16 ch x 12 u32-slots = 384 threads, once
    if (t < 2 * CC * 12) {
        const int buf = t / (CC * 12);
        const int rem = t - buf * (CC * 12);
        const int c = rem / 12, s = rem - (rem / 12) * 12;
        const int e = (s < 4) ? (2 * s) : (392 + 2 * (s - 4));
        *(unsigned*)&xp[buf][c][e] = 0u;
    }

    const float sw  = swp[0];
    const float sch = spacings[b * 2 + 0] * invtheta[0];   // H axis
    const float scw = spacings[b * 2 + 1] * invtheta[1];   // W axis
    float kh[5], kw[5];                                    // symmetric taps j=0..4
#pragma unroll
    for (int j = 0; j < 5; ++j) {
        float dh = sch * (float)(j - 5); kh[j] = __expf(-0.5f * dh * dh);
        float dw = scw * (float)(j - 5); kw[j] = __expf(-0.5f * dw * dw);
    }

    const int ca = t / 48, ga = t - (t / 48) * 48;   // A/C identity
    const int colB = t >> 1, halfB = (t & 1) * 8;    // B identity (pair-split)

    const size_t cbase = (size_t)b * CHW + (size_t)ca * HWSZ + (size_t)ga * 8;

    const uint4 z4 = make_uint4(0u, 0u, 0u, 0u);
    uint4 win[11];
    if (MODE >= 1) {
        const ushortT* tin = (const ushortT*)in0;
#pragma unroll
        for (int j = 0; j < 11; ++j) {
            const int r = h0 + j - 5;
            win[j] = ((unsigned)r < HH) ? *(const uint4*)(tin + cbase + (size_t)r * WW) : z4;
        }
    }

    __syncthreads();   // pads visible

    auto row_body = [&](const int h, const int buf) {
        // ---------------- A: x-row -> LDS (bf16) ----------------
        if (MODE == 0) {
            const float* xf = (const float*)in0;
            const float4 A  = *(const float4*)(xf + cbase + (size_t)h * WW);
            const float4 Bq = *(const float4*)(xf + cbase + (size_t)h * WW + 4);
            float v[8] = {A.x, A.y, A.z, A.w, Bq.x, Bq.y, Bq.z, Bq.w};
            const uint4 q = pk8(v);
            *(uint4*)(x0b_out + cbase + (size_t)h * WW) = q;
            *(uint4*)&xp[buf][ca][8 + ga * 8] = q;
        } else {
            const ushortT* tin = (const ushortT*)in0;
            const int nr = h + 6;
            const uint4 nt = (nr < HH) ? *(const uint4*)(tin + cbase + (size_t)nr * WW) : z4;
            const uint4 uq = *(const uint4*)(x0b + cbase + (size_t)h * WW);
            float acc[8];
#pragma unroll
            for (int k = 0; k < 8; ++k) acc[k] = 0.f;
#pragma unroll
            for (int j = 0; j < 5; ++j) {            // symmetric row pairs (j, 10-j)
                float e1[8], e2[8];
                unpk8(win[j], e1); unpk8(win[10 - j], e2);
                const float kj = kh[j];
#pragma unroll
                for (int k = 0; k < 8; ++k) acc[k] = fmaf(kj, e1[k] + e2[k], acc[k]);
            }
            float uu[8]; unpk8(uq, uu);
            float xv[8];
#pragma unroll
            for (int k = 0; k < 8; ++k) xv[k] = fmaf(sw, acc[k], uu[k]);
            *(uint4*)&xp[buf][ca][8 + ga * 8] = pk8(xv);
#pragma unroll
            for (int j = 0; j < 10; ++j) win[j] = win[j + 1];
            win[10] = nt;
        }
        __syncthreads();

        // ---------------- B: per-column softmax (all 768 lanes) ----------------
        {
            float xr[8];
#pragma unroll
            for (int cc = 0; cc < 8; ++cc) xr[cc] = bf2f(xp[buf][halfB + cc][8 + colB]);
            float mh = xr[0];
#pragma unroll
            for (int cc = 1; cc < 8; ++cc) mh = fmaxf(mh, xr[cc]);
            const float m = fmaxf(mh, __shfl_xor(mh, 1));
            float e[8]; float shs = 0.f;
#pragma unroll
            for (int cc = 0; cc < 8; ++cc) { e[cc] = __expf(xr[cc] - m); shs += e[cc]; }
            const float s = shs + __shfl_xor(shs, 1);
            if (MODE <= 1) {
                const float inv = 1.0f / s;
#pragma unroll
                for (int cc = 0; cc < 8; ++cc)
                    xp[buf][halfB + cc][8 + colB] = f2bf(e[cc] * inv);
            } else {
                if (!(t & 1)) l_lds[colB] = m + __logf(s);
            }
        }
        __syncthreads();

        // ---------------- C: ConvW -> t' / final output ----------------
        if (MODE <= 1) {
            const uint4 q0 = *(const uint4*)&xp[buf][ca][ga * 8];
            const uint4 q1 = *(const uint4*)&xp[buf][ca][ga * 8 + 8];
            const uint4 q2 = *(const uint4*)&xp[buf][ca][ga * 8 + 16];
            float w[24];
            unpk8(q0, w); unpk8(q1, w + 8); unpk8(q2, w + 16);
            float o[8];
#pragma unroll
            for (int k = 0; k < 8; ++k) {
                float a = 0.f;
#pragma unroll
                for (int j = 0; j < 5; ++j)          // symmetric col pairs
                    a = fmaf(kw[j], w[k + j + 3] + w[k + 13 - j], a);
                o[k] = a;
            }
            *(uint4*)((ushortT*)outp + cbase + (size_t)h * WW) = pk8(o);
        } else {
            const uint4 xq = *(const uint4*)&xp[buf][ca][8 + ga * 8];
            float xv[8]; unpk8(xq, xv);
            const float4 l0 = *(const float4*)&l_lds[ga * 8];
            const float4 l1 = *(const float4*)&l_lds[ga * 8 + 4];
            float* op = (float*)outp + cbase + (size_t)h * WW;
            *(float4*)op       = make_float4(xv[0]-l0.x, xv[1]-l0.y, xv[2]-l0.z, xv[3]-l0.w);
            *(float4*)(op + 4) = make_float4(xv[4]-l1.x, xv[5]-l1.y, xv[6]-l1.z, xv[7]-l1.w);
        }
    };

    for (int hh = h0; hh < h0 + ROWS; hh += 2) {
        row_body(hh,     0);
        row_body(hh + 1, 1);
    }
}

// ---------------------------------------------------------------------------
extern "C" void kernel_launch(void* const* d_in, const int* in_sizes, int n_in,
                              void* d_out, int out_size, void* d_ws, size_t ws_size,
                              hipStream_t stream)
{
    const float* x0   = (const float*)d_in[0];  // (B,C,H,W) f32
    const float* spac = (const float*)d_in[1];  // (B,2)
    const float* sw   = (const float*)d_in[2];  // scalar
    const float* it   = (const float*)d_in[3];  // (2,)

    ushortT* tA  = (ushortT*)d_ws;              // 75.5 MB
    ushortT* tB  = tA + (size_t)NPIX;           // 75.5 MB
    ushortT* x0b = tB + (size_t)NPIX;           // 75.5 MB
    float*   out = (float*)d_out;

    dim3 gf(HSEGS, BB);   // (32,16) = 512 blocks
    dim3 bf(FT);

    // iter 1: t0 = ConvW(softmax(x0)); also emits x0b
    k_fused<0><<<gf, bf, 0, stream>>>(x0, nullptr, tA, x0b, spac, it, sw);
    // iters 2..5: t_{n+1} = ConvW(softmax(x0b + sw*ConvH(t_n)))
    k_fused<1><<<gf, bf, 0, stream>>>(tA, x0b, tB, nullptr, spac, it, sw);
    k_fused<1><<<gf, bf, 0, stream>>>(tB, x0b, tA, nullptr, spac, it, sw);
    k_fused<1><<<gf, bf, 0, stream>>>(tA, x0b, tB, nullptr, spac, it, sw);
    k_fused<1><<<gf, bf, 0, stream>>>(tB, x0b, tA, nullptr, spac, it, sw);
    // final: out = log_softmax(x0b + sw*ConvH(t4))
    k_fused<2><<<gf, bf, 0, stream>>>(tA, x0b, out, nullptr, spac, it, sw);
}

// Round 9
// 408.062 us; speedup vs baseline: 1.3749x; 1.0511x over previous
//
#include <hip/hip_runtime.h>
#include <hip/hip_bf16.h>

#define BB 16
#define CC 16
#define HH 384
#define WW 384
#define HWSZ (HH*WW)
#define CHW (CC*HWSZ)
#define NPIX (BB*CHW)

#define FT 768             // 16 channels x 48 col-groups
#define ROWS 12            // rows per block -> 32x16 = 512 blocks
#define HSEGS (HH/ROWS)
#define SROW 408           // LDS row: 8 pad | 384 | 16 pad (bf16 elems)

typedef unsigned short ushortT;

// ---- bf16 helpers ---------------------------------------------------------
__device__ __forceinline__ void unpk2(unsigned u, float& lo, float& hi) {
    union { unsigned u; float f; } a, b;
    a.u = u << 16; b.u = u & 0xFFFF0000u;
    lo = a.f; hi = b.f;
}
// native RNE pack: compiler emits v_cvt_pk_bf16_f32 (guide m240: beats manual)
__device__ __forceinline__ unsigned pk2(float lo, float hi) {
    __hip_bfloat162 h = __float22bfloat162_rn(make_float2(lo, hi));
    union { __hip_bfloat162 h; unsigned u; } c; c.h = h;
    return c.u;
}
__device__ __forceinline__ void unpk8(const uint4& q, float* v) {
    unpk2(q.x, v[0], v[1]); unpk2(q.y, v[2], v[3]);
    unpk2(q.z, v[4], v[5]); unpk2(q.w, v[6], v[7]);
}
__device__ __forceinline__ uint4 pk8(const float* v) {
    uint4 q;
    q.x = pk2(v[0], v[1]); q.y = pk2(v[2], v[3]);
    q.z = pk2(v[4], v[5]); q.w = pk2(v[6], v[7]);
    return q;
}
// quad-perm DPP cross-lane (VALU pipe, not DS): 0xB1 = xor1, 0x4E = xor2
template<int CTRL>
__device__ __forceinline__ float dpp_f(float x) {
    union { float f; int i; } c; c.f = x;
    union { int i; float f; } r;
    r.i = __builtin_amdgcn_update_dpp(0, c.i, CTRL, 0xF, 0xF, true);
    return r.f;
}

// ---------------------------------------------------------------------------
// Fused CRF step, 2-row phases.
//  MODE 0: in0 = x0 (f32); emits x0b (bf16) and t0.
//  MODE 1: in0 = t_n (bf16) + x0b; emits t_{n+1}.
//  MODE 2: in0 = t_4 (bf16) + x0b; emits log_softmax(x5) f32.
// Per pair of rows: P1 = { C(prev pair) overlapped with A(cur pair) }, bar,
//                   P2 = { B softmax (u32 col-pairs + DPP quad reduce) }, bar.
// 4 LDS row-buffers; 12 barriers/block (was 24).
// ---------------------------------------------------------------------------
template<int MODE>
__global__ __launch_bounds__(FT) void k_fused(
    const void* __restrict__ in0, const ushortT* __restrict__ x0b,
    void* __restrict__ outp, ushortT* __restrict__ x0b_out,
    const float* __restrict__ spacings, const float* __restrict__ invtheta,
    const float* __restrict__ swp)
{
    __shared__ ushortT xp[4][CC][SROW];          // 52224 B
    __shared__ __align__(16) float l_lds[2][WW]; // MODE 2 only

    const int t  = threadIdx.x;
    const int b  = blockIdx.y;
    const int h0 = blockIdx.x * ROWS;

    {   // zero pads: 4 buf x 16 ch x 12 u32-slots = 768 threads, one each
        const int buf = t / (CC * 12);
        const int rem = t - buf * (CC * 12);
        const int c = rem / 12, s = rem - (rem / 12) * 12;
        const int e = (s < 4) ? (2 * s) : (392 + 2 * (s - 4));
        *(unsigned*)&xp[buf][c][e] = 0u;
    }

    const float sw  = swp[0];
    const float sch = spacings[b * 2 + 0] * invtheta[0];   // H axis
    const float scw = spacings[b * 2 + 1] * invtheta[1];   // W axis
    float kh[5], kw[5];                                    // symmetric taps
#pragma unroll
    for (int j = 0; j < 5; ++j) {
        float dh = sch * (float)(j - 5); kh[j] = __expf(-0.5f * dh * dh);
        float dw = scw * (float)(j - 5); kw[j] = __expf(-0.5f * dw * dw);
    }

    const int ca = t / 48, ga = t - (t / 48) * 48;   // A/C identity
    const int cp = t >> 2, qq = t & 3;               // B identity (col-pair, ch-quad)

    const size_t cbase = (size_t)b * CHW + (size_t)ca * HWSZ + (size_t)ga * 8;
    const uint4 z4 = make_uint4(0u, 0u, 0u, 0u);

    // 12-slot rolling window: W[j] = t-row (h-5+j), rows h..h+1 use [0..10]/[1..11]
    uint4 W[12];
    if (MODE >= 1) {
        const ushortT* tin = (const ushortT*)in0;
#pragma unroll
        for (int j = 0; j < 12; ++j) {
            const int r = h0 + j - 5;
            W[j] = ((unsigned)r < HH) ? *(const uint4*)(tin + cbase + (size_t)r * WW) : z4;
        }
    }

    __syncthreads();   // pads visible

    auto A_row_m0 = [&](int h, int buf) {
        const float* xf = (const float*)in0;
        const float4 A0 = *(const float4*)(xf + cbase + (size_t)h * WW);
        const float4 A1 = *(const float4*)(xf + cbase + (size_t)h * WW + 4);
        float v[8] = {A0.x, A0.y, A0.z, A0.w, A1.x, A1.y, A1.z, A1.w};
        const uint4 q = pk8(v);
        *(uint4*)(x0b_out + cbase + (size_t)h * WW) = q;
        *(uint4*)&xp[buf][ca][8 + ga * 8] = q;
    };

    auto A_row = [&](int o, int buf, uint4 uq) {     // ConvH from W[o..o+10] + add
        float acc[8];
#pragma unroll
        for (int k = 0; k < 8; ++k) acc[k] = 0.f;
#pragma unroll
        for (int j = 0; j < 5; ++j) {                // symmetric pairs (o+j, o+10-j)
            float e1[8], e2[8];
            unpk8(W[o + j], e1); unpk8(W[o + 10 - j], e2);
            const float kj = kh[j];
#pragma unroll
            for (int k = 0; k < 8; ++k) acc[k] = fmaf(kj, e1[k] + e2[k], acc[k]);
        }
        float uu[8]; unpk8(uq, uu);
        float xv[8];
#pragma unroll
        for (int k = 0; k < 8; ++k) xv[k] = fmaf(sw, acc[k], uu[k]);
        *(uint4*)&xp[buf][ca][8 + ga * 8] = pk8(xv);
    };

    auto B_row = [&](int buf, int r) {
        float xa[4], xb[4];
#pragma unroll
        for (int i = 0; i < 4; ++i) {
            const unsigned u = *(const unsigned*)&xp[buf][qq * 4 + i][8 + 2 * cp];
            unpk2(u, xa[i], xb[i]);
        }
        float m0 = fmaxf(fmaxf(xa[0], xa[1]), fmaxf(xa[2], xa[3]));
        float m1 = fmaxf(fmaxf(xb[0], xb[1]), fmaxf(xb[2], xb[3]));
        m0 = fmaxf(m0, dpp_f<0xB1>(m0)); m0 = fmaxf(m0, dpp_f<0x4E>(m0));
        m1 = fmaxf(m1, dpp_f<0xB1>(m1)); m1 = fmaxf(m1, dpp_f<0x4E>(m1));
        float e0[4], e1[4], s0 = 0.f, s1 = 0.f;
#pragma unroll
        for (int i = 0; i < 4; ++i) {
            e0[i] = __expf(xa[i] - m0); s0 += e0[i];
            e1[i] = __expf(xb[i] - m1); s1 += e1[i];
        }
        s0 += dpp_f<0xB1>(s0); s0 += dpp_f<0x4E>(s0);
        s1 += dpp_f<0xB1>(s1); s1 += dpp_f<0x4E>(s1);
        if (MODE <= 1) {
            const float i0 = 1.0f / s0, i1 = 1.0f / s1;
#pragma unroll
            for (int i = 0; i < 4; ++i)
                *(unsigned*)&xp[buf][qq * 4 + i][8 + 2 * cp] = pk2(e0[i] * i0, e1[i] * i1);
        } else {
            if (qq == 0) {
                l_lds[r][2 * cp]     = m0 + __logf(s0);
                l_lds[r][2 * cp + 1] = m1 + __logf(s1);
            }
        }
    };

    auto C_row = [&](int h, int buf, int r) {
        if (MODE <= 1) {
            const uint4 q0 = *(const uint4*)&xp[buf][ca][ga * 8];
            const uint4 q1 = *(const uint4*)&xp[buf][ca][ga * 8 + 8];
            const uint4 q2 = *(const uint4*)&xp[buf][ca][ga * 8 + 16];
            float w[24];
            unpk8(q0, w); unpk8(q1, w + 8); unpk8(q2, w + 16);
            float o[8];
#pragma unroll
            for (int k = 0; k < 8; ++k) {
                float a = 0.f;
#pragma unroll
                for (int j = 0; j < 5; ++j)
                    a = fmaf(kw[j], w[k + 3 + j] + w[k + 13 - j], a);
                o[k] = a;
            }
            *(uint4*)((ushortT*)outp + cbase + (size_t)h * WW) = pk8(o);
        } else {
            const uint4 xq = *(const uint4*)&xp[buf][ca][8 + ga * 8];
            float xv[8]; unpk8(xq, xv);
            const float4 l0 = *(const float4*)&l_lds[r][ga * 8];
            const float4 l1 = *(const float4*)&l_lds[r][ga * 8 + 4];
            float* op = (float*)outp + cbase + (size_t)h * WW;
            *(float4*)op       = make_float4(xv[0]-l0.x, xv[1]-l0.y, xv[2]-l0.z, xv[3]-l0.w);
            *(float4*)(op + 4) = make_float4(xv[4]-l1.x, xv[5]-l1.y, xv[6]-l1.z, xv[7]-l1.w);
        }
    };

#pragma unroll
    for (int p = 0; p < 6; ++p) {
        const int h  = h0 + 2 * p;
        const int bA = 2 * (p & 1);
        const int bC = 2 * ((p & 1) ^ 1);

        // ---- P1: C(prev) overlapped with loads + A(cur) ----
        if (MODE == 0) {
            if (p > 0) { C_row(h - 2, bC, 0); C_row(h - 1, bC + 1, 1); }
            A_row_m0(h, bA); A_row_m0(h + 1, bA + 1);
        } else {
            if (p > 0) { C_row(h - 2, bC, 0); C_row(h - 1, bC + 1, 1); }
            const ushortT* tin = (const ushortT*)in0;
            const uint4 uq0 = *(const uint4*)(x0b + cbase + (size_t)h * WW);
            const uint4 uq1 = *(const uint4*)(x0b + cbase + (size_t)(h + 1) * WW);
            uint4 nt0 = z4, nt1 = z4;
            if (p < 5) {
                const int r0 = h + 7, r1 = h + 8;
                if (r0 < HH) nt0 = *(const uint4*)(tin + cbase + (size_t)r0 * WW);
                if (r1 < HH) nt1 = *(const uint4*)(tin + cbase + (size_t)r1 * WW);
            }
            A_row(0, bA,     uq0);
            A_row(1, bA + 1, uq1);
            if (p < 5) {
#pragma unroll
                for (int j = 0; j < 10; ++j) W[j] = W[j + 2];
                W[10] = nt0; W[11] = nt1;
            }
        }
        __syncthreads();

        // ---- P2: softmax both rows ----
        B_row(bA, 0);
        B_row(bA + 1, 1);
        __syncthreads();
    }
    // epilogue: C of last pair (bufs 2,3)
    C_row(h0 + 10, 2, 0);
    C_row(h0 + 11, 3, 1);
}

// ---------------------------------------------------------------------------
extern "C" void kernel_launch(void* const* d_in, const int* in_sizes, int n_in,
                              void* d_out, int out_size, void* d_ws, size_t ws_size,
                              hipStream_t stream)
{
    const float* x0   = (const float*)d_in[0];  // (B,C,H,W) f32
    const float* spac = (const float*)d_in[1];  // (B,2)
    const float* sw   = (const float*)d_in[2];  // scalar
    const float* it   = (const float*)d_in[3];  // (2,)

    ushortT* tA  = (ushortT*)d_ws;              // 75.5 MB
    ushortT* tB  = tA + (size_t)NPIX;           // 75.5 MB
    ushortT* x0b = tB + (size_t)NPIX;           // 75.5 MB
    float*   out = (float*)d_out;

    dim3 gf(HSEGS, BB);   // (32,16) = 512 blocks
    dim3 bf(FT);

    // iter 1: t0 = ConvW(softmax(x0)); also emits x0b
    k_fused<0><<<gf, bf, 0, stream>>>(x0, nullptr, tA, x0b, spac, it, sw);
    // iters 2..5: t_{n+1} = ConvW(softmax(x0b + sw*ConvH(t_n)))
    k_fused<1><<<gf, bf, 0, stream>>>(tA, x0b, tB, nullptr, spac, it, sw);
    k_fused<1><<<gf, bf, 0, stream>>>(tB, x0b, tA, nullptr, spac, it, sw);
    k_fused<1><<<gf, bf, 0, stream>>>(tA, x0b, tB, nullptr, spac, it, sw);
    k_fused<1><<<gf, bf, 0, stream>>>(tB, x0b, tA, nullptr, spac, it, sw);
    // final: out = log_softmax(x0b + sw*ConvH(t4))
    k_fused<2><<<gf, bf, 0, stream>>>(tA, x0b, out, nullptr, spac, it, sw);
}